// Round 1
// baseline (126.166 us; speedup 1.0000x reference)
//
#include <hip/hip_runtime.h>

// QuadraticConv2D: B=8 H=56 W=56 C=64 O=128, 55 quadratic pairs over (ones + 9 shifts)
// out[b,h,w,o] = sum_{p,c} S[i_p][c]*S[j_p][c] * K[p][c][o]
// GEMM M=25088 (pixels), K=3520 (55 pairs x 64 ch), N=128, A generated on the fly.

#define CB 8
#define CH 56
#define CW 56
#define CC 64
#define CO 128
#define NPAIR 55
#define RS 68   // rowsF stride in floats (68*4B=272B: 16B-aligned, odd bank-quad -> conflict-free)
#define QS 72   // Q stride in bf16 (72*2B=144B: 16B-aligned, odd bank-quad -> 2-way max)

typedef __attribute__((ext_vector_type(8))) short bf8_t;   // 8 x bf16 (4 VGPRs) MFMA frag
typedef __attribute__((ext_vector_type(4))) float f4_t;    // MFMA accumulator frag

__device__ __forceinline__ unsigned short pack_bf16(float f) {
  unsigned u = __float_as_uint(f);
  return (unsigned short)((u + 0x8000u) >> 16);  // round-to-nearest (half-up); plenty for 0.17 abs tol
}

// ---- prep: kernel [55][64][128] f32 -> Bt [55][128][64] bf16 (B^T layout: n-major, k contiguous)
__global__ __launch_bounds__(256) void prep_kernel(const float* __restrict__ K,
                                                   unsigned short* __restrict__ Bt) {
  __shared__ float tile[CC * CO];
  const int p = blockIdx.x;
  const int t = threadIdx.x;
  const float* src = K + (size_t)p * CC * CO;
#pragma unroll
  for (int e = 0; e < 8; ++e) {
    const int idx = t * 4 + e * 1024;
    *(float4*)&tile[idx] = *(const float4*)&src[idx];
  }
  __syncthreads();
  const int n = t & 127;
  const int kh = t >> 7;  // k-half: 0 or 1
  unsigned short ov[32];
#pragma unroll
  for (int k = 0; k < 32; ++k)
    ov[k] = pack_bf16(tile[(kh * 32 + k) * CO + n]);
  unsigned short* dst = Bt + ((size_t)p * CO + n) * CC + kh * 32;
#pragma unroll
  for (int g = 0; g < 4; ++g)
    *(bf8_t*)(dst + g * 8) = *(const bf8_t*)&ov[g * 8];
}

// ---- main: one block per (b,h) image row. 256 threads = 4 waves.
// Wave w: N-range [w*32, w*32+32); M = 64 (56 real pixels + 8 pad).
__global__ __launch_bounds__(256, 2) void quad_kernel(const float* __restrict__ in,
                                                      const unsigned short* __restrict__ Bt,
                                                      float* __restrict__ out) {
  __shared__ float rowsF[3][64][RS];  // 3 input rows, col = w+1 (halo), f32, 52.2 KB
  __shared__ short Q[64][QS];         // quad tile for current pair, bf16 bits, 9.2 KB

  const int t = threadIdx.x;
  const int b = blockIdx.x / CH;
  const int h = blockIdx.x % CH;

  // stage 3 input rows into LDS with zero halo (w=-1, w=56) and zero out-of-image rows
  {
    const int col = t >> 2;           // 0..63
    const int cg = (t & 3) * 16;      // channel group of 16
    const int w = col - 1;
#pragma unroll
    for (int r = 0; r < 3; ++r) {
      const int hh = h + r - 1;
      const bool valid = (hh >= 0) && (hh < CH) && (w >= 0) && (w < CW);
      float4 v0 = make_float4(0.f, 0.f, 0.f, 0.f), v1 = v0, v2 = v0, v3 = v0;
      if (valid) {
        const float* s = in + (((size_t)(b * CH + hh)) * CW + w) * CC + cg;
        v0 = *(const float4*)(s);
        v1 = *(const float4*)(s + 4);
        v2 = *(const float4*)(s + 8);
        v3 = *(const float4*)(s + 12);
      }
      float* d = &rowsF[r][col][cg];
      *(float4*)(d) = v0;
      *(float4*)(d + 4) = v1;
      *(float4*)(d + 8) = v2;
      *(float4*)(d + 12) = v3;
    }
  }

  const int lane = t & 63;
  const int wid = t >> 6;
  const int nl = lane & 15;   // MFMA n / m lane index
  const int qd4 = lane >> 4;  // MFMA quad (k-group / row-group)

  f4_t acc[4][2];
#pragma unroll
  for (int mt = 0; mt < 4; ++mt)
#pragma unroll
    for (int nt = 0; nt < 2; ++nt)
      acc[mt][nt] = (f4_t){0.f, 0.f, 0.f, 0.f};

  // B-frag base for this lane: Bt[p][n][k], n = wid*32 + nt*16 + nl, k = ks*32 + qd4*8
  const unsigned short* Bl = Bt + ((size_t)(wid * 32 + nl)) * CC + qd4 * 8;
  bf8_t bcur[2][2], bnext[2][2];
#pragma unroll
  for (int nt = 0; nt < 2; ++nt)
#pragma unroll
    for (int ks = 0; ks < 2; ++ks)
      bcur[nt][ks] = *(const bf8_t*)(Bl + nt * 16 * CC + ks * 32);

  const int gm = t >> 2;          // gen: pixel m (0..63)
  const int gc = (t & 3) * 16;    // gen: channel group

  int pi = 0, pj = 0;
#pragma unroll 1
  for (int p = 0; p < NPAIR; ++p) {
    // ---- generate Q[m][c] = S_pi[m][c] * S_pj[m][c] (bf16)
    {
      float va[16], vb[16];
      if (pi > 0) {
        const int s = pi - 1, rr = s / 3, sc = s % 3;
        int colA = gm + sc; colA = colA > 63 ? 63 : colA;  // pad-m rows read zeros/garbage, masked later
        const float* pa = &rowsF[rr][colA][gc];
#pragma unroll
        for (int g = 0; g < 4; ++g) {
          float4 v = *(const float4*)(pa + g * 4);
          va[g * 4 + 0] = v.x; va[g * 4 + 1] = v.y; va[g * 4 + 2] = v.z; va[g * 4 + 3] = v.w;
        }
      } else {
#pragma unroll
        for (int e = 0; e < 16; ++e) va[e] = 1.f;
      }
      if (pj > 0) {
        const int s = pj - 1, rr = s / 3, sc = s % 3;
        int colB = gm + sc; colB = colB > 63 ? 63 : colB;
        const float* pb = &rowsF[rr][colB][gc];
#pragma unroll
        for (int g = 0; g < 4; ++g) {
          float4 v = *(const float4*)(pb + g * 4);
          vb[g * 4 + 0] = v.x; vb[g * 4 + 1] = v.y; vb[g * 4 + 2] = v.z; vb[g * 4 + 3] = v.w;
        }
      } else {
#pragma unroll
        for (int e = 0; e < 16; ++e) vb[e] = 1.f;
      }
      unsigned short qv[16];
#pragma unroll
      for (int e = 0; e < 16; ++e) qv[e] = pack_bf16(va[e] * vb[e]);
      short* qp = &Q[gm][gc];
      *(bf8_t*)(qp) = *(const bf8_t*)&qv[0];
      *(bf8_t*)(qp + 8) = *(const bf8_t*)&qv[8];
    }
    // prefetch next pair's B-frags (L2-resident; latency hidden across barrier+mfma)
    if (p < NPAIR - 1) {
      const unsigned short* bp = Bl + (size_t)(p + 1) * CO * CC;
#pragma unroll
      for (int nt = 0; nt < 2; ++nt)
#pragma unroll
        for (int ks = 0; ks < 2; ++ks)
          bnext[nt][ks] = *(const bf8_t*)(bp + nt * 16 * CC + ks * 32);
    }
    __syncthreads();  // Q written
    // ---- MFMA: K=64 (2 ksteps of 32)
#pragma unroll
    for (int ks = 0; ks < 2; ++ks) {
      bf8_t a[4];
#pragma unroll
      for (int mt = 0; mt < 4; ++mt)
        a[mt] = *(const bf8_t*)&Q[mt * 16 + nl][ks * 32 + qd4 * 8];
#pragma unroll
      for (int mt = 0; mt < 4; ++mt)
#pragma unroll
        for (int nt = 0; nt < 2; ++nt)
          acc[mt][nt] = __builtin_amdgcn_mfma_f32_16x16x32_bf16(a[mt], bcur[nt][ks], acc[mt][nt], 0, 0, 0);
    }
    __syncthreads();  // Q reads done before next pair overwrites
#pragma unroll
    for (int nt = 0; nt < 2; ++nt)
#pragma unroll
      for (int ks = 0; ks < 2; ++ks)
        bcur[nt][ks] = bnext[nt][ks];
    ++pj;
    if (pj == 10) { ++pi; pj = pi; }
  }

  // ---- epilogue: C/D layout col=lane&15 (n), row=(lane>>4)*4+reg (m)
  float* obase = out + ((size_t)(b * CH + h) * CW) * CO + wid * 32;
#pragma unroll
  for (int mt = 0; mt < 4; ++mt)
#pragma unroll
    for (int r4 = 0; r4 < 4; ++r4) {
      const int wp = mt * 16 + qd4 * 4 + r4;
      if (wp < CW) {
#pragma unroll
        for (int nt = 0; nt < 2; ++nt)
          obase[(size_t)wp * CO + nt * 16 + nl] = acc[mt][nt][r4];
      }
    }
}

extern "C" void kernel_launch(void* const* d_in, const int* in_sizes, int n_in,
                              void* d_out, int out_size, void* d_ws, size_t ws_size,
                              hipStream_t stream) {
  const float* in = (const float*)d_in[0];      // [8,56,56,64] f32
  const float* K = (const float*)d_in[1];       // [55,64,128] f32
  float* out = (float*)d_out;                   // [8,56,56,128] f32
  unsigned short* Bt = (unsigned short*)d_ws;   // [55][128][64] bf16 = 901,120 B
  (void)in_sizes; (void)n_in; (void)out_size; (void)ws_size;

  prep_kernel<<<NPAIR, 256, 0, stream>>>(K, Bt);
  quad_kernel<<<CB * CH, 256, 0, stream>>>(in, Bt, out);
}